// Round 11
// baseline (1802.293 us; speedup 1.0000x reference)
//
#include <hip/hip_runtime.h>
#include <cstdio>
#include <cstdint>

typedef _Float16 f16;
typedef f16 hf2   __attribute__((ext_vector_type(2)));
typedef f16 f16x8 __attribute__((ext_vector_type(8)));
typedef float f32x4 __attribute__((ext_vector_type(4)));
typedef unsigned int   u32;
typedef unsigned short u16;

#define B_    256
#define S_    512
#define IN_   32
#define H_    256
#define G3_   768
#define D_    32
#define PRED_ 96
#define TC_   16     // in-kernel time sub-chunk (steps per LDS stage)
#define KP_   72     // padded h k-slice (halves): 64 data + 8 pad

#if __has_builtin(__builtin_amdgcn_fdot2)
__device__ __forceinline__ float fdot2(hf2 a, hf2 b, float c) {
  return __builtin_amdgcn_fdot2(a, b, c, false);
}
#else
__device__ __forceinline__ float fdot2(hf2 a, hf2 b, float c) {
  return c + (float)a[0] * (float)b[0] + (float)a[1] * (float)b[1];
}
#endif

__device__ __forceinline__ float sigm(float x) {
  return __builtin_amdgcn_rcpf(1.f + __expf(-x));
}
__device__ __forceinline__ float tanh_fast(float x) {
  return 1.f - 2.f * __builtin_amdgcn_rcpf(__expf(2.f * x) + 1.f);
}
__device__ __forceinline__ hf2 bc2(u32 v) { return __builtin_bit_cast(hf2, v); }

__global__ void f32_to_f16_k(const float* __restrict__ in, f16* __restrict__ out, int n) {
  int i = blockIdx.x * blockDim.x + threadIdx.x;
  if (i < n) out[i] = (f16)in[i];
}

// biasc[n] = bih[n] + (n<512 ? bhh[n] : 0)  — r,z gate bhh folded into xp.
__global__ void make_bias(const float* __restrict__ bih, const float* __restrict__ bhh,
                          float* __restrict__ out) {
  int i = blockIdx.x * blockDim.x + threadIdx.x;
  if (i < G3_) out[i] = bih[i] + (i < 512 ? bhh[i] : 0.f);
}

__device__ __forceinline__ f16x8 cvt8(const float* p) {
  float4 lo = ((const float4*)p)[0];
  float4 hi = ((const float4*)p)[1];
  f16x8 r;
  r[0] = (f16)lo.x; r[1] = (f16)lo.y; r[2] = (f16)lo.z; r[3] = (f16)lo.w;
  r[4] = (f16)hi.x; r[5] = (f16)hi.y; r[6] = (f16)hi.z; r[7] = (f16)hi.w;
  return r;
}

// ------- chunked xp GEMM: xp_chunk = A_chunk @ Wih^T + biasc (f16 out) ------
// WG = 256 thr (4 waves). Each block computes a 64-row x 768-col tile.
template <int KK>   // 32: A = f32 x;  256: A = f16 (h1 chunk)
__global__ __launch_bounds__(256) void gemm_xp(
    const void* __restrict__ Asrc, size_t aBlk, int tl_rows,
    const f16* __restrict__ Wih,     // f16 [768][KK]
    const float* __restrict__ biasc, // [768]
    u16* __restrict__ xp) {          // chunk-local [B*tl_rows][768] f16
  const int tid = threadIdx.x;
  const int wv = tid >> 6, lane = tid & 63, lm = lane & 15, q = lane >> 4;
  const int tiles_pb = tl_rows >> 6;
  const int b = blockIdx.x / tiles_pb, hf = blockIdx.x % tiles_pb;
  const size_t arow0 = (size_t)b * aBlk + (size_t)(hf * 64) * KK;
  const size_t orow0 = (size_t)b * tl_rows + hf * 64;

#pragma unroll 1
  for (int nt = 0; nt < 12; ++nt) {
    const int n0 = wv * 192 + nt * 16;
    const f16* Bp = Wih + (size_t)(n0 + lm) * KK + q * 8;
    f32x4 acc[4];
#pragma unroll
    for (int j = 0; j < 4; ++j) acc[j] = f32x4{0.f, 0.f, 0.f, 0.f};
#pragma unroll
    for (int k0 = 0; k0 < KK; k0 += 32) {
      f16x8 bv = *(const f16x8*)(Bp + k0);
#pragma unroll
      for (int j = 0; j < 4; ++j) {
        f16x8 av;
        if constexpr (KK == 32) {
          av = cvt8((const float*)Asrc + arow0 + (size_t)(j * 16 + lm) * KK + k0 + q * 8);
        } else {
          av = *(const f16x8*)((const f16*)Asrc + arow0 + (size_t)(j * 16 + lm) * KK + k0 + q * 8);
        }
        acc[j] = __builtin_amdgcn_mfma_f32_16x16x32_f16(av, bv, acc[j], 0, 0, 0);
      }
    }
    const float bb = biasc[n0 + lm];
#pragma unroll
    for (int j = 0; j < 4; ++j)
#pragma unroll
      for (int r = 0; r < 4; ++r)   // D: col=lane&15 (n), row=q*4+r (m)
        xp[(orow0 + j * 16 + q * 4 + r) * G3_ + n0 + lm] =
            __builtin_bit_cast(u16, (f16)(acc[j][r] + bb));
  }
}

// ---------------- dual-layer recurrence kernel (512 thr/WG) -----------------
// WGs [0, nwg0) run LAYER-0 chunk c; WGs [nwg0, grid) run LAYER-1 chunk c-1 —
// the two are data-independent, and with LDS trimmed to ~34KB + VGPR<=128,
// TWO WGs co-reside per CU (16 waves). Each WG's per-step stalls (LDS turn,
// barrier, gate chain) are filled by the other WG's fdot2 stream — attacking
// the measured 40% stall at 2 waves/SIMD (rounds 7/10: w-size and
// bank-conflict changes were both ~neutral at ~3500 cyc/step).
// Inner loop = round-10 partition: thread (p2=tid>>2, kh=tid&3) owns units
// {2p2, 2p2+1}, k-slice [kh*64, kh*64+64) -> w = 96 VGPRs stationary.
__global__ __launch_bounds__(512, 2) void gru_rec2(
    const u16* __restrict__ xp0,     // layer0 chunk-local [B*tl][768] f16
    const u16* __restrict__ xp1,     // layer1 chunk-local [B*tl][768] f16
    const f16* __restrict__ W0,      // f16 [768][256]
    const f16* __restrict__ W1,
    const float* __restrict__ bhh0,  // [768]
    const float* __restrict__ bhh1,
    float* __restrict__ hst0,        // f32 [B][256]
    float* __restrict__ hst1,
    f16* __restrict__ h1c,           // chunk-local [B*tl][256] (layer0 out)
    int tl, int first0, int first1, int nwg0) {
  const int role = (int)(blockIdx.x >= (unsigned)nwg0);
  const int b = blockIdx.x - (role ? nwg0 : 0);
  const u16* xp = role ? xp1 : xp0;
  const f16* Whh16 = role ? W1 : W0;
  const float* bhh = role ? bhh1 : bhh0;
  float* hstate = role ? hst1 : hst0;
  const int first = role ? first1 : first0;

  const int tid = threadIdx.x;
  const int p2 = tid >> 2, kh = tid & 3;
  const int u0 = p2 * 2;

  // ---- W_hh -> registers (once): 2 units x 3 gates x 8 uint4 = 96 VGPRs ----
  uint4 w0[3][8], w1[3][8];
#pragma unroll
  for (int g = 0; g < 3; ++g)
#pragma unroll
    for (int t = 0; t < 8; ++t) {
      w0[g][t] = ((const uint4*)Whh16)[(size_t)(g * 256 + u0) * 32 + kh * 8 + t];
      w1[g][t] = ((const uint4*)Whh16)[(size_t)(g * 256 + u0 + 1) * 32 + kh * 8 + t];
    }
  const int myu = u0 + kh;                       // unit this thread finalizes (kh<2)
  const float bhn = (kh < 2) ? bhh[512 + myu] : 0.f;

  __shared__ u16 xbuf[TC_ * G3_];                // 24,576 B (single-buffered)
  __shared__ __align__(16) u16 hbuf[2][4 * KP_]; // 1,152 B (padded k-slices)
  __shared__ u16 hhist[TC_ * H_];                // 8,192 B
  // total ~34 KB -> 2 WGs/CU

  float h = 0.f;
  if (kh < 2) {
    h = first ? 0.f : hstate[b * H_ + myu];
    hbuf[0][(myu >> 6) * KP_ + (myu & 63)] = __builtin_bit_cast(u16, (f16)h);
  }
  int cur = 0;
  const uint4* xsrc = (const uint4*)xp + (size_t)b * tl * 96;  // 96 uint4/row
  const int nsub = tl / TC_;

#pragma unroll 1
  for (int c2 = 0; c2 < nsub; ++c2) {
    // ---- stage sub-chunk: 24KB = 1536 uint4, 3 per thread ----
    // (prev sub-chunk's last step ends with __syncthreads -> WAR safe)
    {
      const uint4* src = xsrc + (size_t)c2 * 1536;
      uint4* dst = (uint4*)xbuf;
      uint4 v0 = src[tid], v1 = src[512 + tid], v2 = src[1024 + tid];
      dst[tid] = v0; dst[512 + tid] = v1; dst[1024 + tid] = v2;
    }
    __syncthreads();   // xbuf visible; also covers hbuf[0] init

#pragma unroll 1
    for (int tl_i = 0; tl_i < TC_; ++tl_i) {
      // kh's k-slice: 8 uint4 at padded offset kh*KP_ (banks disjoint per kh)
      const uint4* hb = (const uint4*)(hbuf[cur] + kh * KP_);
      float a0r = 0.f, a0z = 0.f, a0n = 0.f, a1r = 0.f, a1z = 0.f, a1n = 0.f;
#pragma unroll
      for (int cc = 0; cc < 8; ++cc) {
        uint4 hv = hb[cc];
        uint4 wa = w0[0][cc], wb = w0[1][cc], wc = w0[2][cc];
        uint4 wd = w1[0][cc], we = w1[1][cc], wf = w1[2][cc];
        a0r = fdot2(bc2(wa.x), bc2(hv.x), a0r);
        a0z = fdot2(bc2(wb.x), bc2(hv.x), a0z);
        a0n = fdot2(bc2(wc.x), bc2(hv.x), a0n);
        a1r = fdot2(bc2(wd.x), bc2(hv.x), a1r);
        a1z = fdot2(bc2(we.x), bc2(hv.x), a1z);
        a1n = fdot2(bc2(wf.x), bc2(hv.x), a1n);
        a0r = fdot2(bc2(wa.y), bc2(hv.y), a0r);
        a0z = fdot2(bc2(wb.y), bc2(hv.y), a0z);
        a0n = fdot2(bc2(wc.y), bc2(hv.y), a0n);
        a1r = fdot2(bc2(wd.y), bc2(hv.y), a1r);
        a1z = fdot2(bc2(we.y), bc2(hv.y), a1z);
        a1n = fdot2(bc2(wf.y), bc2(hv.y), a1n);
        a0r = fdot2(bc2(wa.z), bc2(hv.z), a0r);
        a0z = fdot2(bc2(wb.z), bc2(hv.z), a0z);
        a0n = fdot2(bc2(wc.z), bc2(hv.z), a0n);
        a1r = fdot2(bc2(wd.z), bc2(hv.z), a1r);
        a1z = fdot2(bc2(we.z), bc2(hv.z), a1z);
        a1n = fdot2(bc2(wf.z), bc2(hv.z), a1n);
        a0r = fdot2(bc2(wa.w), bc2(hv.w), a0r);
        a0z = fdot2(bc2(wb.w), bc2(hv.w), a0z);
        a0n = fdot2(bc2(wc.w), bc2(hv.w), a0n);
        a1r = fdot2(bc2(wd.w), bc2(hv.w), a1r);
        a1z = fdot2(bc2(we.w), bc2(hv.w), a1z);
        a1n = fdot2(bc2(wf.w), bc2(hv.w), a1n);
      }
      // reduce over the 4 kh threads (lanes p2*4 + {0..3})
      a0r += __shfl_xor(a0r, 1); a0r += __shfl_xor(a0r, 2);
      a0z += __shfl_xor(a0z, 1); a0z += __shfl_xor(a0z, 2);
      a0n += __shfl_xor(a0n, 1); a0n += __shfl_xor(a0n, 2);
      a1r += __shfl_xor(a1r, 1); a1r += __shfl_xor(a1r, 2);
      a1z += __shfl_xor(a1z, 1); a1z += __shfl_xor(a1z, 2);
      a1n += __shfl_xor(a1n, 1); a1n += __shfl_xor(a1n, 2);

      if (kh < 2) {      // thread kh finalizes unit u0+kh
        const float ar = (kh == 0) ? a0r : a1r;
        const float az = (kh == 0) ? a0z : a1z;
        const float an = (kh == 0) ? a0n : a1n;
        const u16* xrow = xbuf + tl_i * G3_;
        float xr = (float)__builtin_bit_cast(f16, xrow[myu]);
        float xz = (float)__builtin_bit_cast(f16, xrow[256 + myu]);
        float xn = (float)__builtin_bit_cast(f16, xrow[512 + myu]);
        float r = sigm(xr + ar);                 // bhh_r folded into xp
        float z = sigm(xz + az);                 // bhh_z folded into xp
        float n = tanh_fast(xn + r * (an + bhn));
        h = n + z * (h - n);
        const u16 h16v = __builtin_bit_cast(u16, (f16)h);
        hbuf[cur ^ 1][(myu >> 6) * KP_ + (myu & 63)] = h16v;
        if (!role) hhist[tl_i * H_ + myu] = h16v;
      }
      __syncthreads();   // step reads done AND step writes visible
      cur ^= 1;
    }

    if (!role) {
      // coalesced sub-chunk flush: 8KB, one uint4 per thread (tid<512)
      uint4 hv0 = ((const uint4*)hhist)[tid];
      ((uint4*)(h1c + ((size_t)b * tl + c2 * TC_) * H_))[tid] = hv0;
      // next stage's __syncthreads orders these reads vs. hhist rewrite
    }
  }
  if (kh < 2) hstate[b * H_ + myu] = h;
}

// ---------------- projection + 96-step rollout ------------------------------
__global__ __launch_bounds__(128) void proj_rollout(
    const float* __restrict__ hfinal, const float* __restrict__ Wp,
    const float* __restrict__ bp, const float* __restrict__ Cm,
    const float* __restrict__ rld, const float* __restrict__ rtd,
    const float* __restrict__ rg, const float* __restrict__ om,
    float* __restrict__ out) {
  const int b = blockIdx.x, tid = threadIdx.x;
  __shared__ float fh[256];
  __shared__ float sb[128];
  ((float2*)fh)[tid] = ((const float2*)(hfinal + b * 256))[tid];
  __syncthreads();
  const float4* wrow = (const float4*)(Wp + tid * 256);
  float acc = 0.f;
#pragma unroll 16
  for (int k4 = 0; k4 < 64; k4++) {
    float4 wv = wrow[k4];
    acc += wv.x * fh[4 * k4] + wv.y * fh[4 * k4 + 1] + wv.z * fh[4 * k4 + 2] +
           wv.w * fh[4 * k4 + 3];
  }
  sb[tid] = acc + bp[tid];
  __syncthreads();
  if (tid < 32) {
    const int dd = tid;
    float s0 = sb[dd * 4], s1 = sb[dd * 4 + 1], s2 = sb[dd * 4 + 2], s3 = sb[dd * 4 + 3];
    float al = sigm(rld[dd]) * 0.15f + 0.85f;
    float at = sigm(rtd[dd]) * 0.25f + 0.70f;
    float g  = sigm(rg[dd]) * 0.20f + 0.80f;
    float cw = cosf(om[dd]), sw = sinf(om[dd]);
    float r00 = g * cw, r01 = -g * sw, r10 = g * sw, r11 = g * cw;
    float c0 = Cm[dd * 4], c1 = Cm[dd * 4 + 1], c2 = Cm[dd * 4 + 2], c3 = Cm[dd * 4 + 3];
    float* op = out + (size_t)b * PRED_ * D_ + dd;
    for (int t = 0; t < PRED_; t++) {
      float n0 = s0 * al, n1 = s1 * at;
      float n2 = s2 * r00 + s3 * r10;
      float n3 = s2 * r01 + s3 * r11;
      op[(size_t)t * D_] = c0 * n0 + c1 * n1 + c2 * n2 + c3 * n3;
      s0 = n0; s1 = n1; s2 = n2; s3 = n3;
    }
  }
}

extern "C" void kernel_launch(void* const* d_in, const int* in_sizes, int n_in,
                              void* d_out, int out_size, void* d_ws,
                              size_t ws_size, hipStream_t stream) {
  (void)in_sizes; (void)n_in; (void)out_size;
  const float* x     = (const float*)d_in[0];
  const float* Wih0  = (const float*)d_in[1];
  const float* Whh0  = (const float*)d_in[2];
  const float* bih0  = (const float*)d_in[3];
  const float* bhh0  = (const float*)d_in[4];
  const float* Wih1  = (const float*)d_in[5];
  const float* Whh1  = (const float*)d_in[6];
  const float* bih1  = (const float*)d_in[7];
  const float* bhh1  = (const float*)d_in[8];
  const float* Wproj = (const float*)d_in[9];
  const float* bproj = (const float*)d_in[10];
  const float* Cm    = (const float*)d_in[11];
  const float* rld   = (const float*)d_in[12];
  const float* rtd   = (const float*)d_in[13];
  const float* rg    = (const float*)d_in[14];
  const float* om    = (const float*)d_in[15];
  float* out = (float*)d_out;

  char* ws = (char*)d_ws;
  const int TL = 64;
  // layout
  const size_t wi0_off  = 0;           //    49,152
  const size_t wi1_off  = 49152;       //   393,216
  const size_t whh0_off = 442368;      //   393,216
  const size_t whh1_off = 835584;      //   393,216
  const size_t b0_off   = 1228800;     //     3,072
  const size_t b1_off   = 1231872;     //     3,072
  const size_t hs0_off  = 1234944;     //   262,144 (f32 [B][256])
  const size_t hs1_off  = 1497088;     //   262,144
  const size_t h1c_off  = 1759232;     // B*TL*256*2  =  8,388,608
  const size_t xp0_off  = 10147840;    // B*TL*768*2  = 25,165,824
  const size_t xp1_off  = 35313664;    // B*TL*768*2  = 25,165,824
  const size_t need     = 60479488;

  if (ws_size < need) {
    fprintf(stderr, "kernel_launch: ws too small: have %zu need %zu — skipping\n",
            ws_size, need);
    return;
  }

  f16* wi016   = (f16*)(ws + wi0_off);
  f16* wi116   = (f16*)(ws + wi1_off);
  f16* whh016  = (f16*)(ws + whh0_off);
  f16* whh116  = (f16*)(ws + whh1_off);
  float* bias0 = (float*)(ws + b0_off);
  float* bias1 = (float*)(ws + b1_off);
  float* hst0  = (float*)(ws + hs0_off);
  float* hst1  = (float*)(ws + hs1_off);
  f16* h1c     = (f16*)(ws + h1c_off);
  u16* xp0     = (u16*)(ws + xp0_off);
  u16* xp1     = (u16*)(ws + xp1_off);

  f32_to_f16_k<<<96, 256, 0, stream>>>(Wih0, wi016, G3_ * IN_);
  f32_to_f16_k<<<768, 256, 0, stream>>>(Wih1, wi116, G3_ * H_);
  f32_to_f16_k<<<768, 256, 0, stream>>>(Whh0, whh016, G3_ * H_);
  f32_to_f16_k<<<768, 256, 0, stream>>>(Whh1, whh116, G3_ * H_);
  make_bias<<<3, 256, 0, stream>>>(bih0, bhh0, bias0);
  make_bias<<<3, 256, 0, stream>>>(bih1, bhh1, bias1);

  const int nchunks = S_ / TL;   // 8
  // pipeline: combo(c) = rec0(chunk c) ∥ rec1(chunk c-1)
  gemm_xp<IN_><<<B_, 256, 0, stream>>>(
      (const void*)x, (size_t)S_ * IN_, TL, wi016, bias0, xp0);
  gru_rec2<<<B_, 512, 0, stream>>>(xp0, xp1, whh016, whh116, bhh0, bhh1,
                                   hst0, hst1, h1c, TL, 1, 0, B_);
  for (int c = 1; c < nchunks; ++c) {
    gemm_xp<H_><<<B_, 256, 0, stream>>>(
        (const void*)h1c, (size_t)TL * H_, TL, wi116, bias1, xp1);
    gemm_xp<IN_><<<B_, 256, 0, stream>>>(
        (const void*)(x + (size_t)c * TL * IN_), (size_t)S_ * IN_, TL, wi016, bias0, xp0);
    gru_rec2<<<2 * B_, 512, 0, stream>>>(xp0, xp1, whh016, whh116, bhh0, bhh1,
                                         hst0, hst1, h1c, TL, 0, (c == 1) ? 1 : 0, B_);
  }
  gemm_xp<H_><<<B_, 256, 0, stream>>>(
      (const void*)h1c, (size_t)TL * H_, TL, wi116, bias1, xp1);
  gru_rec2<<<B_, 512, 0, stream>>>(xp0, xp1, whh016, whh116, bhh0, bhh1,
                                   hst0, hst1, h1c, TL, 0, 0, 0);  // drain: all role-1
  proj_rollout<<<B_, 128, 0, stream>>>(hst1, Wproj, bproj, Cm, rld, rtd, rg, om, out);
}

// Round 12
// 1526.855 us; speedup vs baseline: 1.1804x; 1.1804x over previous
//
#include <hip/hip_runtime.h>
#include <cstdio>
#include <cstdint>

typedef _Float16 f16;
typedef f16 hf2   __attribute__((ext_vector_type(2)));
typedef f16 f16x8 __attribute__((ext_vector_type(8)));
typedef float f32x4 __attribute__((ext_vector_type(4)));
typedef unsigned int   u32;
typedef unsigned short u16;

#define B_    256
#define S_    512
#define IN_   32
#define H_    256
#define G3_   768
#define D_    32
#define PRED_ 96
#define TC_   32     // in-kernel time sub-chunk (steps per LDS stage)
#define KP_   72     // padded h k-slice (halves): 64 data + 8 pad

#if __has_builtin(__builtin_amdgcn_fdot2)
__device__ __forceinline__ float fdot2(hf2 a, hf2 b, float c) {
  return __builtin_amdgcn_fdot2(a, b, c, false);
}
#else
__device__ __forceinline__ float fdot2(hf2 a, hf2 b, float c) {
  return c + (float)a[0] * (float)b[0] + (float)a[1] * (float)b[1];
}
#endif

// DPP cross-lane adds on the VALU pipe (HIP __shfl_xor lowers to
// ds_bpermute/ds_swizzle = LDS pipe; at 12 shuffles/thread/step that is
// ~576 LDS-pipe cyc/step/CU — round-11 analysis). quad_perm stays within
// 4-lane groups, exactly our kh reduction domain.
__device__ __forceinline__ float dpp_add_xor1(float x) {
  int y = __builtin_amdgcn_mov_dpp(__builtin_bit_cast(int, x), 0xB1, 0xF, 0xF, true);
  return x + __builtin_bit_cast(float, y);   // quad_perm [1,0,3,2]
}
__device__ __forceinline__ float dpp_add_xor2(float x) {
  int y = __builtin_amdgcn_mov_dpp(__builtin_bit_cast(int, x), 0x4E, 0xF, 0xF, true);
  return x + __builtin_bit_cast(float, y);   // quad_perm [2,3,0,1]
}

__device__ __forceinline__ float sigm(float x) {
  return __builtin_amdgcn_rcpf(1.f + __expf(-x));
}
__device__ __forceinline__ float tanh_fast(float x) {
  return 1.f - 2.f * __builtin_amdgcn_rcpf(__expf(2.f * x) + 1.f);
}
__device__ __forceinline__ hf2 bc2(u32 v) { return __builtin_bit_cast(hf2, v); }

__global__ void f32_to_f16_k(const float* __restrict__ in, f16* __restrict__ out, int n) {
  int i = blockIdx.x * blockDim.x + threadIdx.x;
  if (i < n) out[i] = (f16)in[i];
}

// biasc[n] = bih[n] + (n<512 ? bhh[n] : 0)  — r,z gate bhh folded into xp.
__global__ void make_bias(const float* __restrict__ bih, const float* __restrict__ bhh,
                          float* __restrict__ out) {
  int i = blockIdx.x * blockDim.x + threadIdx.x;
  if (i < G3_) out[i] = bih[i] + (i < 512 ? bhh[i] : 0.f);
}

__device__ __forceinline__ f16x8 cvt8(const float* p) {
  float4 lo = ((const float4*)p)[0];
  float4 hi = ((const float4*)p)[1];
  f16x8 r;
  r[0] = (f16)lo.x; r[1] = (f16)lo.y; r[2] = (f16)lo.z; r[3] = (f16)lo.w;
  r[4] = (f16)hi.x; r[5] = (f16)hi.y; r[6] = (f16)hi.z; r[7] = (f16)hi.w;
  return r;
}

// ------- chunked xp GEMM: xp_chunk = A_chunk @ Wih^T + biasc (f16 out) ------
// WG = 256 thr (4 waves). Each block computes a 64-row x 768-col tile.
template <int KK>   // 32: A = f32 x;  256: A = f16 (h1 chunk)
__global__ __launch_bounds__(256) void gemm_xp(
    const void* __restrict__ Asrc, size_t aBlk, int tl_rows,
    const f16* __restrict__ Wih,     // f16 [768][KK]
    const float* __restrict__ biasc, // [768]
    u16* __restrict__ xp) {          // chunk-local [B*tl_rows][768] f16
  const int tid = threadIdx.x;
  const int wv = tid >> 6, lane = tid & 63, lm = lane & 15, q = lane >> 4;
  const int tiles_pb = tl_rows >> 6;
  const int b = blockIdx.x / tiles_pb, hf = blockIdx.x % tiles_pb;
  const size_t arow0 = (size_t)b * aBlk + (size_t)(hf * 64) * KK;
  const size_t orow0 = (size_t)b * tl_rows + hf * 64;

#pragma unroll 1
  for (int nt = 0; nt < 12; ++nt) {
    const int n0 = wv * 192 + nt * 16;
    const f16* Bp = Wih + (size_t)(n0 + lm) * KK + q * 8;
    f32x4 acc[4];
#pragma unroll
    for (int j = 0; j < 4; ++j) acc[j] = f32x4{0.f, 0.f, 0.f, 0.f};
#pragma unroll
    for (int k0 = 0; k0 < KK; k0 += 32) {
      f16x8 bv = *(const f16x8*)(Bp + k0);
#pragma unroll
      for (int j = 0; j < 4; ++j) {
        f16x8 av;
        if constexpr (KK == 32) {
          av = cvt8((const float*)Asrc + arow0 + (size_t)(j * 16 + lm) * KK + k0 + q * 8);
        } else {
          av = *(const f16x8*)((const f16*)Asrc + arow0 + (size_t)(j * 16 + lm) * KK + k0 + q * 8);
        }
        acc[j] = __builtin_amdgcn_mfma_f32_16x16x32_f16(av, bv, acc[j], 0, 0, 0);
      }
    }
    const float bb = biasc[n0 + lm];
#pragma unroll
    for (int j = 0; j < 4; ++j)
#pragma unroll
      for (int r = 0; r < 4; ++r)   // D: col=lane&15 (n), row=q*4+r (m)
        xp[(orow0 + j * 16 + q * 4 + r) * G3_ + n0 + lm] =
            __builtin_bit_cast(u16, (f16)(acc[j][r] + bb));
  }
}

// ---------------- pure-VALU recurrence kernel (512 thr) ---------------------
// One WG (512 thr, 8 waves) per batch row; tl_rows steps from f32 hstate.
// Thread (p2=tid>>2, kh=tid&3) owns units {2*p2, 2*p2+1} (all 3 gates) with
// k-slice [kh*64, kh*64+64) -> w = 2 units x 3 gates x 8 uint4 = 96 VGPRs.
// Round-12 change vs round-10 (only one): kh reduction via DPP quad-perm adds
// (VALU pipe) instead of __shfl_xor (LDS pipe) — removes ~576 LDS-pipe
// cyc/step/CU from a kernel measured VALU+LDS co-bound.
template <int LAYER>
__global__ __launch_bounds__(512, 2) void gru_rec(
    const u16* __restrict__ xp,      // chunk-local [B*tl_rows][768] f16
    const f16* __restrict__ Whh16,   // f16 [768][256]
    const float* __restrict__ bhh,   // [768] (n-gate slice used)
    float* __restrict__ hstate,      // f32 [B][256], in+out across chunks
    f16* __restrict__ h1c,           // chunk-local [B*tl_rows][256] (LAYER==0)
    int tl_rows, int first) {
  const int b   = blockIdx.x;
  const int tid = threadIdx.x;
  const int p2 = tid >> 2, kh = tid & 3;
  const int u0 = p2 * 2;

  // ---- W_hh -> registers (once): 2 units x 3 gates x 8 uint4 = 96 VGPRs ----
  uint4 w0[3][8], w1[3][8];
#pragma unroll
  for (int g = 0; g < 3; ++g)
#pragma unroll
    for (int t = 0; t < 8; ++t) {
      w0[g][t] = ((const uint4*)Whh16)[(size_t)(g * 256 + u0) * 32 + kh * 8 + t];
      w1[g][t] = ((const uint4*)Whh16)[(size_t)(g * 256 + u0 + 1) * 32 + kh * 8 + t];
    }
  const int myu = u0 + kh;                       // unit this thread finalizes (kh<2)
  const float bhn = (kh < 2) ? bhh[512 + myu] : 0.f;

  __shared__ u16 xbuf[2][TC_ * G3_];             // 98,304 B
  __shared__ __align__(16) u16 hbuf[2][4 * KP_]; // 1,152 B (padded k-slices)
  __shared__ u16 hhist[TC_ * H_];                // 16,384 B

  float h = 0.f;
  if (kh < 2) {
    h = first ? 0.f : hstate[b * H_ + myu];
    hbuf[0][(myu >> 6) * KP_ + (myu & 63)] = __builtin_bit_cast(u16, (f16)h);
  }
  int cur = 0;
  const uint4* xsrc = (const uint4*)xp + (size_t)b * tl_rows * 96;  // 96 uint4/row
  const int nsub = tl_rows >> 5;

#pragma unroll 1
  for (int c2 = 0; c2 < nsub; ++c2) {
    // ---- stage sub-chunk: 48KB = 3072 uint4, 2 passes x 3/thread ----
    {
      const uint4* src = xsrc + (size_t)c2 * 3072;
      uint4* dst = (uint4*)xbuf[c2 & 1];
#pragma unroll
      for (int pass = 0; pass < 2; ++pass) {
        uint4 v0 = src[(pass * 3 + 0) * 512 + tid];
        uint4 v1 = src[(pass * 3 + 1) * 512 + tid];
        uint4 v2 = src[(pass * 3 + 2) * 512 + tid];
        dst[(pass * 3 + 0) * 512 + tid] = v0;
        dst[(pass * 3 + 1) * 512 + tid] = v1;
        dst[(pass * 3 + 2) * 512 + tid] = v2;
      }
    }
    __syncthreads();   // xbuf visible; also covers hbuf[0] init / prior writes
    const u16* xrow0 = xbuf[c2 & 1];

#pragma unroll 1
    for (int tl = 0; tl < TC_; ++tl) {
      // kh's k-slice: 8 uint4 at padded offset kh*KP_ (banks disjoint per kh)
      const uint4* hb = (const uint4*)(hbuf[cur] + kh * KP_);
      float a0r = 0.f, a0z = 0.f, a0n = 0.f, a1r = 0.f, a1z = 0.f, a1n = 0.f;
#pragma unroll
      for (int cc = 0; cc < 8; ++cc) {
        uint4 hv = hb[cc];
        uint4 wa = w0[0][cc], wb = w0[1][cc], wc = w0[2][cc];
        uint4 wd = w1[0][cc], we = w1[1][cc], wf = w1[2][cc];
        a0r = fdot2(bc2(wa.x), bc2(hv.x), a0r);
        a0z = fdot2(bc2(wb.x), bc2(hv.x), a0z);
        a0n = fdot2(bc2(wc.x), bc2(hv.x), a0n);
        a1r = fdot2(bc2(wd.x), bc2(hv.x), a1r);
        a1z = fdot2(bc2(we.x), bc2(hv.x), a1z);
        a1n = fdot2(bc2(wf.x), bc2(hv.x), a1n);
        a0r = fdot2(bc2(wa.y), bc2(hv.y), a0r);
        a0z = fdot2(bc2(wb.y), bc2(hv.y), a0z);
        a0n = fdot2(bc2(wc.y), bc2(hv.y), a0n);
        a1r = fdot2(bc2(wd.y), bc2(hv.y), a1r);
        a1z = fdot2(bc2(we.y), bc2(hv.y), a1z);
        a1n = fdot2(bc2(wf.y), bc2(hv.y), a1n);
        a0r = fdot2(bc2(wa.z), bc2(hv.z), a0r);
        a0z = fdot2(bc2(wb.z), bc2(hv.z), a0z);
        a0n = fdot2(bc2(wc.z), bc2(hv.z), a0n);
        a1r = fdot2(bc2(wd.z), bc2(hv.z), a1r);
        a1z = fdot2(bc2(we.z), bc2(hv.z), a1z);
        a1n = fdot2(bc2(wf.z), bc2(hv.z), a1n);
        a0r = fdot2(bc2(wa.w), bc2(hv.w), a0r);
        a0z = fdot2(bc2(wb.w), bc2(hv.w), a0z);
        a0n = fdot2(bc2(wc.w), bc2(hv.w), a0n);
        a1r = fdot2(bc2(wd.w), bc2(hv.w), a1r);
        a1z = fdot2(bc2(we.w), bc2(hv.w), a1z);
        a1n = fdot2(bc2(wf.w), bc2(hv.w), a1n);
      }
      // reduce over the 4 kh threads (lanes p2*4 + {0..3}) — DPP, VALU pipe
      a0r = dpp_add_xor2(dpp_add_xor1(a0r));
      a0z = dpp_add_xor2(dpp_add_xor1(a0z));
      a0n = dpp_add_xor2(dpp_add_xor1(a0n));
      a1r = dpp_add_xor2(dpp_add_xor1(a1r));
      a1z = dpp_add_xor2(dpp_add_xor1(a1z));
      a1n = dpp_add_xor2(dpp_add_xor1(a1n));

      if (kh < 2) {      // thread kh finalizes unit u0+kh
        const float ar = (kh == 0) ? a0r : a1r;
        const float az = (kh == 0) ? a0z : a1z;
        const float an = (kh == 0) ? a0n : a1n;
        const u16* xrow = xrow0 + tl * G3_;
        float xr = (float)__builtin_bit_cast(f16, xrow[myu]);
        float xz = (float)__builtin_bit_cast(f16, xrow[256 + myu]);
        float xn = (float)__builtin_bit_cast(f16, xrow[512 + myu]);
        float r = sigm(xr + ar);                 // bhh_r folded into xp
        float z = sigm(xz + az);                 // bhh_z folded into xp
        float n = tanh_fast(xn + r * (an + bhn));
        h = n + z * (h - n);
        const u16 h16v = __builtin_bit_cast(u16, (f16)h);
        hbuf[cur ^ 1][(myu >> 6) * KP_ + (myu & 63)] = h16v;
        if constexpr (LAYER == 0) hhist[tl * H_ + myu] = h16v;
      }
      __syncthreads();   // step-t reads done AND step-t writes visible
      cur ^= 1;
    }

    if constexpr (LAYER == 0) {
      // coalesced sub-chunk flush: 16KB, two uint4 per thread.
      // (next stage's __syncthreads orders these reads vs. hhist rewrite)
      uint4 hv0 = ((const uint4*)hhist)[tid];
      uint4 hv1 = ((const uint4*)hhist)[512 + tid];
      uint4* dst = (uint4*)(h1c + ((size_t)b * tl_rows + c2 * TC_) * H_);
      dst[tid] = hv0;
      dst[512 + tid] = hv1;
    }
  }
  if (kh < 2) hstate[b * H_ + myu] = h;
}

// ---------------- projection + 96-step rollout ------------------------------
__global__ __launch_bounds__(128) void proj_rollout(
    const float* __restrict__ hfinal, const float* __restrict__ Wp,
    const float* __restrict__ bp, const float* __restrict__ Cm,
    const float* __restrict__ rld, const float* __restrict__ rtd,
    const float* __restrict__ rg, const float* __restrict__ om,
    float* __restrict__ out) {
  const int b = blockIdx.x, tid = threadIdx.x;
  __shared__ float fh[256];
  __shared__ float sb[128];
  ((float2*)fh)[tid] = ((const float2*)(hfinal + b * 256))[tid];
  __syncthreads();
  const float4* wrow = (const float4*)(Wp + tid * 256);
  float acc = 0.f;
#pragma unroll 16
  for (int k4 = 0; k4 < 64; k4++) {
    float4 wv = wrow[k4];
    acc += wv.x * fh[4 * k4] + wv.y * fh[4 * k4 + 1] + wv.z * fh[4 * k4 + 2] +
           wv.w * fh[4 * k4 + 3];
  }
  sb[tid] = acc + bp[tid];
  __syncthreads();
  if (tid < 32) {
    const int dd = tid;
    float s0 = sb[dd * 4], s1 = sb[dd * 4 + 1], s2 = sb[dd * 4 + 2], s3 = sb[dd * 4 + 3];
    float al = sigm(rld[dd]) * 0.15f + 0.85f;
    float at = sigm(rtd[dd]) * 0.25f + 0.70f;
    float g  = sigm(rg[dd]) * 0.20f + 0.80f;
    float cw = cosf(om[dd]), sw = sinf(om[dd]);
    float r00 = g * cw, r01 = -g * sw, r10 = g * sw, r11 = g * cw;
    float c0 = Cm[dd * 4], c1 = Cm[dd * 4 + 1], c2 = Cm[dd * 4 + 2], c3 = Cm[dd * 4 + 3];
    float* op = out + (size_t)b * PRED_ * D_ + dd;
    for (int t = 0; t < PRED_; t++) {
      float n0 = s0 * al, n1 = s1 * at;
      float n2 = s2 * r00 + s3 * r10;
      float n3 = s2 * r01 + s3 * r11;
      op[(size_t)t * D_] = c0 * n0 + c1 * n1 + c2 * n2 + c3 * n3;
      s0 = n0; s1 = n1; s2 = n2; s3 = n3;
    }
  }
}

extern "C" void kernel_launch(void* const* d_in, const int* in_sizes, int n_in,
                              void* d_out, int out_size, void* d_ws,
                              size_t ws_size, hipStream_t stream) {
  (void)in_sizes; (void)n_in; (void)out_size;
  const float* x     = (const float*)d_in[0];
  const float* Wih0  = (const float*)d_in[1];
  const float* Whh0  = (const float*)d_in[2];
  const float* bih0  = (const float*)d_in[3];
  const float* bhh0  = (const float*)d_in[4];
  const float* Wih1  = (const float*)d_in[5];
  const float* Whh1  = (const float*)d_in[6];
  const float* bih1  = (const float*)d_in[7];
  const float* bhh1  = (const float*)d_in[8];
  const float* Wproj = (const float*)d_in[9];
  const float* bproj = (const float*)d_in[10];
  const float* Cm    = (const float*)d_in[11];
  const float* rld   = (const float*)d_in[12];
  const float* rtd   = (const float*)d_in[13];
  const float* rg    = (const float*)d_in[14];
  const float* om    = (const float*)d_in[15];
  float* out = (float*)d_out;

  char* ws = (char*)d_ws;
  // fixed region
  const size_t wi0_off  = 0;           //    49,152
  const size_t wi1_off  = 49152;       //   393,216
  const size_t whh0_off = 442368;      //   393,216
  const size_t whh1_off = 835584;      //   393,216
  const size_t b0_off   = 1228800;     //     3,072
  const size_t b1_off   = 1231872;     //     3,072
  const size_t hs0_off  = 1234944;     //   262,144 (f32 [B][256])
  const size_t hs1_off  = 1497088;     //   262,144
  const size_t h1c_off  = 1759232;     // h1 chunk: B*TL*256*2
  // xpc follows h1c; sizes depend on TL.
  const size_t need64  = h1c_off + (size_t)B_ * 64 * H_ * 2  + (size_t)B_ * 64 * G3_ * 2;   // 35,313,664
  const size_t need128 = h1c_off + (size_t)B_ * 128 * H_ * 2 + (size_t)B_ * 128 * G3_ * 2;  // 68,868,096

  if (ws_size < need64) {
    fprintf(stderr, "kernel_launch: ws too small: have %zu need %zu — skipping\n",
            ws_size, need64);
    return;
  }
  const int TL = (ws_size >= need128) ? 128 : 64;
  const size_t xpc_off = h1c_off + (size_t)B_ * TL * H_ * 2;

  f16* wi016   = (f16*)(ws + wi0_off);
  f16* wi116   = (f16*)(ws + wi1_off);
  f16* whh016  = (f16*)(ws + whh0_off);
  f16* whh116  = (f16*)(ws + whh1_off);
  float* bias0 = (float*)(ws + b0_off);
  float* bias1 = (float*)(ws + b1_off);
  float* hst0  = (float*)(ws + hs0_off);
  float* hst1  = (float*)(ws + hs1_off);
  f16* h1c     = (f16*)(ws + h1c_off);
  u16* xpc     = (u16*)(ws + xpc_off);

  f32_to_f16_k<<<96, 256, 0, stream>>>(Wih0, wi016, G3_ * IN_);
  f32_to_f16_k<<<768, 256, 0, stream>>>(Wih1, wi116, G3_ * H_);
  f32_to_f16_k<<<768, 256, 0, stream>>>(Whh0, whh016, G3_ * H_);
  f32_to_f16_k<<<768, 256, 0, stream>>>(Whh1, whh116, G3_ * H_);
  make_bias<<<3, 256, 0, stream>>>(bih0, bhh0, bias0);
  make_bias<<<3, 256, 0, stream>>>(bih1, bhh1, bias1);

  const int nchunks = S_ / TL;
  const int gblocks = B_ * (TL / 64);
  for (int c = 0; c < nchunks; ++c) {
    gemm_xp<IN_><<<gblocks, 256, 0, stream>>>(
        (const void*)(x + (size_t)c * TL * IN_), (size_t)S_ * IN_, TL, wi016, bias0, xpc);
    gru_rec<0><<<B_, 512, 0, stream>>>(xpc, whh016, bhh0, hst0, h1c, TL, c == 0);
    gemm_xp<H_><<<gblocks, 256, 0, stream>>>(
        (const void*)h1c, (size_t)TL * H_, TL, wi116, bias1, xpc);
    gru_rec<1><<<B_, 512, 0, stream>>>(xpc, whh116, bhh1, hst1, nullptr, TL, c == 0);
  }
  proj_rollout<<<B_, 128, 0, stream>>>(hst1, Wproj, bproj, Cm, rld, rtd, rg, om, out);
}